// Round 3
// baseline (216.462 us; speedup 1.0000x reference)
//
#include <hip/hip_runtime.h>
#include <hip/hip_bf16.h>

// GAT layer, N=8192, F_IN=256, F_OUT=64.
//  k1 : scalar Wh = h@W; f,g projections; Bpack (bf16 B-fragments of Wh).
//  k2 : U = adj@Wh via MFMA; streams adj (256MB) once with depth-1 prefetch;
//       emits edge bitmask Mw and per-row masked max of g (Gmax);
//       epilogue writes Upack (bf16 B-fragments) directly. 32 rows/block.
//  k3 : fused softmax + attention@U + ELU. m_i = leaky(f_i + Gmax_i).
//       Mask+g depth-1 prefetch. 32 rows/block.
//
// Fragment convention (self-consistent, round-1-proven):
//  element e of lane l <-> k = kblock*32 + (l>>4)*8 + e; A row / B col = l&15;
//  C/D: col = l&15, row = (l>>4)*4 + reg.
//  Bpack/Upack: frag[(kb*4+b)*64 + lane][e]  (s16x8 per lane)
//  Mask: Mw[(rowblk16*256 + jb)*8 + e] bit l = adj[rowblk16*16+(l&15)][jb*32+(l>>4)*8+e] > 0

#define N 8192
#define FOUT 64

typedef float f32x4 __attribute__((ext_vector_type(4)));
typedef short s16x8 __attribute__((ext_vector_type(8)));
typedef unsigned long long u64;
typedef u64 u64x2 __attribute__((ext_vector_type(2)));

__device__ __forceinline__ unsigned short f2bf(float x) {
  unsigned u = __float_as_uint(x);
  u += 0x7FFFu + ((u >> 16) & 1u);   // RNE
  return (unsigned short)(u >> 16);
}
__device__ __forceinline__ unsigned pack2(unsigned short lo, unsigned short hi) {
  return (unsigned)lo | ((unsigned)hi << 16);
}

#define MFMA __builtin_amdgcn_mfma_f32_16x16x32_bf16

// ---------------- k1: scalar Wh, f, g, Bpack (round-1-proven) ----------------
__global__ __launch_bounds__(256) void k1(const float* __restrict__ h,
                                          const float* __restrict__ W,
                                          const float* __restrict__ a,
                                          unsigned short* __restrict__ Bpack,
                                          float* __restrict__ f,
                                          float* __restrict__ g) {
  const int lane = threadIdx.x & 63;
  const int w = threadIdx.x >> 6;
  const int i = blockIdx.x * 4 + w;        // row
  const float* hrow = h + (size_t)i * 256;
  float acc = 0.f;
#pragma unroll 8
  for (int k = 0; k < 256; ++k) {
    acc += hrow[k] * W[k * 64 + lane];
  }
  float s1 = acc * a[lane];
  float s2 = acc * a[64 + lane];
#pragma unroll
  for (int d = 32; d > 0; d >>= 1) {
    s1 += __shfl_xor(s1, d);
    s2 += __shfl_xor(s2, d);
  }
  if (lane == 0) { f[i] = s1; g[i] = s2; }
  const int kb = i >> 5;
  const int b = lane >> 4;
  const int lp = (lane & 15) | (((i >> 3) & 3) << 4);
  const int e = i & 7;
  Bpack[(((size_t)(kb * 4 + b)) * 64 + lp) * 8 + e] = f2bf(acc);
}

// ---------------- k2: U = adj@Wh (MFMA) + mask + Gmax; Upack direct ----------------
__global__ __launch_bounds__(512, 4) void k2(const float* __restrict__ adj,
                                             const unsigned short* __restrict__ Bpack,
                                             const float* __restrict__ g,
                                             unsigned short* __restrict__ Upack,
                                             u64* __restrict__ Mw,
                                             float* __restrict__ Gmax) {
  __shared__ float red[8][64][16];   // 32 KB
  __shared__ float gred[8][16];
  const int l = threadIdx.x & 63;
  const int w = threadIdx.x >> 6;
  const int s = w & 1, ph = w >> 1;
  const int i0 = blockIdx.x << 5;          // 32 rows per block
  const int ib = i0 + (s << 4);
  const int r = l & 15, kg = l >> 4;
  const float* aprow = adj + (size_t)(ib + r) * N + (kg << 3);
  const s16x8* Bv = (const s16x8*)Bpack;
  u64* mwbase = Mw + ((size_t)(ib >> 4) << 11);
  f32x4 A0 = {0.f,0.f,0.f,0.f}, A1 = A0, A2 = A0, A3 = A0;
  float gmx = -INFINITY;
  int jb = ph;
  f32x4 a0 = *(const f32x4*)(aprow + (jb << 5));
  f32x4 a1 = *(const f32x4*)(aprow + (jb << 5) + 4);
  for (int t = 0; t < 64; ++t) {
    const int jbn = (t < 63) ? (jb + 4) : jb;
    f32x4 n0 = *(const f32x4*)(aprow + (jbn << 5));
    f32x4 n1 = *(const f32x4*)(aprow + (jbn << 5) + 4);
    const size_t bi = ((size_t)jb << 8) + l;
    s16x8 bf0 = Bv[bi], bf1 = Bv[bi + 64], bf2 = Bv[bi + 128], bf3 = Bv[bi + 192];
    u64 b0 = __ballot(a0.x > 0.f);
    u64 b1 = __ballot(a0.y > 0.f);
    u64 b2 = __ballot(a0.z > 0.f);
    u64 b3 = __ballot(a0.w > 0.f);
    u64 b4 = __ballot(a1.x > 0.f);
    u64 b5 = __ballot(a1.y > 0.f);
    u64 b6 = __ballot(a1.z > 0.f);
    u64 b7 = __ballot(a1.w > 0.f);
    if (l == 0) {
      u64x2* mp = (u64x2*)(mwbase + ((size_t)jb << 3));
      u64x2 v0; v0.x = b0; v0.y = b1;
      u64x2 v1; v1.x = b2; v1.y = b3;
      u64x2 v2; v2.x = b4; v2.y = b5;
      u64x2 v3; v3.x = b6; v3.y = b7;
      mp[0] = v0; mp[1] = v1; mp[2] = v2; mp[3] = v3;
    }
    f32x4 g0 = *(const f32x4*)(g + (jb << 5) + (kg << 3));
    f32x4 g1 = *(const f32x4*)(g + (jb << 5) + (kg << 3) + 4);
    if (a0.x > 0.f) gmx = fmaxf(gmx, g0.x);
    if (a0.y > 0.f) gmx = fmaxf(gmx, g0.y);
    if (a0.z > 0.f) gmx = fmaxf(gmx, g0.z);
    if (a0.w > 0.f) gmx = fmaxf(gmx, g0.w);
    if (a1.x > 0.f) gmx = fmaxf(gmx, g1.x);
    if (a1.y > 0.f) gmx = fmaxf(gmx, g1.y);
    if (a1.z > 0.f) gmx = fmaxf(gmx, g1.z);
    if (a1.w > 0.f) gmx = fmaxf(gmx, g1.w);
    s16x8 af;
    af[0] = (short)f2bf(a0.x); af[1] = (short)f2bf(a0.y);
    af[2] = (short)f2bf(a0.z); af[3] = (short)f2bf(a0.w);
    af[4] = (short)f2bf(a1.x); af[5] = (short)f2bf(a1.y);
    af[6] = (short)f2bf(a1.z); af[7] = (short)f2bf(a1.w);
    A0 = MFMA(af, bf0, A0, 0, 0, 0);
    A1 = MFMA(af, bf1, A1, 0, 0, 0);
    A2 = MFMA(af, bf2, A2, 0, 0, 0);
    A3 = MFMA(af, bf3, A3, 0, 0, 0);
    jb = jbn; a0 = n0; a1 = n1;
  }
  gmx = fmaxf(gmx, __shfl_xor(gmx, 16));
  gmx = fmaxf(gmx, __shfl_xor(gmx, 32));
  if (l < 16) gred[w][l] = gmx;
#pragma unroll
  for (int q = 0; q < 4; ++q) {
    red[w][l][q] = A0[q]; red[w][l][4 + q] = A1[q];
    red[w][l][8 + q] = A2[q]; red[w][l][12 + q] = A3[q];
  }
  __syncthreads();
  const int tl = threadIdx.x & 63;
  const int b = (threadIdx.x >> 6) & 3;
  const int sE = threadIdx.x >> 8;
#pragma unroll
  for (int qq = 0; qq < 2; ++qq) {
    const int idx = (b << 2) + (qq << 1);
    float u0 = 0.f, u1 = 0.f;
#pragma unroll
    for (int j4 = 0; j4 < 4; ++j4) {
      u0 += red[sE + (j4 << 1)][tl][idx];
      u1 += red[sE + (j4 << 1)][tl][idx + 1];
    }
    const int k0 = i0 + (sE << 4) + ((tl >> 4) << 2) + (qq << 1);
    const unsigned pkv = pack2(f2bf(u0), f2bf(u1));
    const int kbD = k0 >> 5, lgrp = (k0 >> 3) & 3, e0 = k0 & 7;
    *(unsigned*)((char*)Upack +
        ((size_t)((kbD << 2) + b) * 64 + ((tl & 15) | (lgrp << 4))) * 16 + (e0 << 1)) = pkv;
  }
  if (threadIdx.x < 32) {
    const int sG = threadIdx.x >> 4, rr = threadIdx.x & 15;
    float gm = -INFINITY;
#pragma unroll
    for (int j4 = 0; j4 < 4; ++j4) gm = fmaxf(gm, gred[sG + (j4 << 1)][rr]);
    Gmax[i0 + (sG << 4) + rr] = gm;
  }
}

// ---------------- k3: fused softmax + attention@U + ELU ----------------
__global__ __launch_bounds__(512, 4) void k3(const u64* __restrict__ Mw,
                                             const unsigned short* __restrict__ Upack,
                                             const float* __restrict__ f,
                                             const float* __restrict__ g,
                                             const float* __restrict__ Gmax,
                                             float* __restrict__ out) {
  __shared__ float red[8][64][16];   // 32 KB
  __shared__ float wred[8][16];
  const int l = threadIdx.x & 63;
  const int w = threadIdx.x >> 6;
  const int s = w & 1, ph = w >> 1;
  const int i0 = blockIdx.x << 5;
  const int ib = i0 + (s << 4);
  const int r = l & 15, kg = l >> 4;
  const float fi = f[ib + r];
  const float gmx = Gmax[ib + r];
  float m = fi + gmx;
  m = fmaxf(m, 0.2f * m);                  // m_i = leaky(f_i + Gmax_i)
  const s16x8* Uv = (const s16x8*)Upack;
  const u64x2* mwb = (const u64x2*)(Mw + ((size_t)(ib >> 4) << 11));
  f32x4 A0 = {0.f,0.f,0.f,0.f}, A1 = A0, A2 = A0, A3 = A0;
  float wsum = 0.f;
  int jb = ph;
  u64x2 m01 = mwb[(jb << 2)], m23 = mwb[(jb << 2) + 1],
        m45 = mwb[(jb << 2) + 2], m67 = mwb[(jb << 2) + 3];
  f32x4 g0 = *(const f32x4*)(g + (jb << 5) + (kg << 3));
  f32x4 g1 = *(const f32x4*)(g + (jb << 5) + (kg << 3) + 4);
  for (int t = 0; t < 64; ++t) {
    const int jbn = (t < 63) ? (jb + 4) : jb;
    u64x2 p01 = mwb[(jbn << 2)], p23 = mwb[(jbn << 2) + 1],
          p45 = mwb[(jbn << 2) + 2], p67 = mwb[(jbn << 2) + 3];
    f32x4 h0 = *(const f32x4*)(g + (jbn << 5) + (kg << 3));
    f32x4 h1 = *(const f32x4*)(g + (jbn << 5) + (kg << 3) + 4);
    const size_t bi = ((size_t)jb << 8) + l;
    s16x8 bf0 = Uv[bi], bf1 = Uv[bi + 64], bf2 = Uv[bi + 128], bf3 = Uv[bi + 192];
    float wt0, wt1, wt2, wt3, wt4, wt5, wt6, wt7;
#define K3E(eo, me, gv) {                                   \
    float x_ = fi + (gv);                                   \
    float ev_ = fmaxf(x_, 0.2f * x_);                       \
    float wv_ = __expf(ev_ - m);                            \
    wv_ = (((me) >> l) & 1ull) ? wv_ : 0.f;                 \
    wsum += wv_; wt##eo = wv_; }
    K3E(0, m01.x, g0.x) K3E(1, m01.y, g0.y)
    K3E(2, m23.x, g0.z) K3E(3, m23.y, g0.w)
    K3E(4, m45.x, g1.x) K3E(5, m45.y, g1.y)
    K3E(6, m67.x, g1.z) K3E(7, m67.y, g1.w)
#undef K3E
    s16x8 pf;
    pf[0] = (short)f2bf(wt0); pf[1] = (short)f2bf(wt1);
    pf[2] = (short)f2bf(wt2); pf[3] = (short)f2bf(wt3);
    pf[4] = (short)f2bf(wt4); pf[5] = (short)f2bf(wt5);
    pf[6] = (short)f2bf(wt6); pf[7] = (short)f2bf(wt7);
    A0 = MFMA(pf, bf0, A0, 0, 0, 0);
    A1 = MFMA(pf, bf1, A1, 0, 0, 0);
    A2 = MFMA(pf, bf2, A2, 0, 0, 0);
    A3 = MFMA(pf, bf3, A3, 0, 0, 0);
    jb = jbn;
    m01 = p01; m23 = p23; m45 = p45; m67 = p67;
    g0 = h0; g1 = h1;
  }
  wsum += __shfl_xor(wsum, 16);
  wsum += __shfl_xor(wsum, 32);
  if (l < 16) wred[w][l] = wsum;
#pragma unroll
  for (int q = 0; q < 4; ++q) {
    red[w][l][q] = A0[q]; red[w][l][4 + q] = A1[q];
    red[w][l][8 + q] = A2[q]; red[w][l][12 + q] = A3[q];
  }
  __syncthreads();
  const int tl = threadIdx.x & 63;
  const int b = (threadIdx.x >> 6) & 3;
  const int sE = threadIdx.x >> 8;
#pragma unroll
  for (int qq = 0; qq < 2; ++qq) {
#pragma unroll
    for (int rr = 0; rr < 2; ++rr) {
      const int reg = (qq << 1) + rr;
      const int idx = (b << 2) + reg;
      const int row = ((tl >> 4) << 2) + reg;
      float sv = 0.f, dv = 0.f;
#pragma unroll
      for (int j4 = 0; j4 < 4; ++j4) {
        sv += red[sE + (j4 << 1)][tl][idx];
        dv += wred[sE + (j4 << 1)][row];
      }
      dv = (dv > 0.f) ? dv : 1.f;            // defensive: avoid 0/0
      float v = sv / dv;
      v = (v > 0.f) ? v : (__expf(v) - 1.f); // ELU
      out[(size_t)(i0 + (sE << 4) + row) * 64 + (b << 4) + (tl & 15)] = v;
    }
  }
}

extern "C" void kernel_launch(void* const* d_in, const int* in_sizes, int n_in,
                              void* d_out, int out_size, void* d_ws, size_t ws_size,
                              hipStream_t stream) {
  const float* h   = (const float*)d_in[0];
  const float* adj = (const float*)d_in[1];
  const float* W   = (const float*)d_in[2];
  const float* a   = (const float*)d_in[3];
  float* out = (float*)d_out;
  char* ws = (char*)d_ws;
  unsigned short* Bpack = (unsigned short*)(ws);                   // 1 MB
  unsigned short* Upack = (unsigned short*)(ws + (1u << 20));      // 1 MB
  float* f    = (float*)(ws + (2u << 20));                         // 32 KB
  float* g    = (float*)(ws + (2u << 20) + 32768u);                // 32 KB
  float* Gmax = (float*)(ws + (2u << 20) + 65536u);                // 32 KB
  u64* Mw = (u64*)(ws + (3u << 20));                               // 8 MB

  hipLaunchKernelGGL(k1, dim3(2048), dim3(256), 0, stream, h, W, a, Bpack, f, g);
  hipLaunchKernelGGL(k2, dim3(256), dim3(512), 0, stream, adj, Bpack, g, Upack, Mw, Gmax);
  hipLaunchKernelGGL(k3, dim3(256), dim3(512), 0, stream, Mw, Upack, f, g, Gmax, out);
}

// Round 4
// 184.178 us; speedup vs baseline: 1.1753x; 1.1753x over previous
//
#include <hip/hip_runtime.h>
#include <hip/hip_bf16.h>

// GAT layer, N=8192, F_IN=256, F_OUT=64.
//  k1 : scalar-ish Wh = h@W (f32x4 h loads); f,g projections; Bpack (bf16 B-frags).
//  k2 : U = adj@Wh via MFMA. 16 rows/block, 512 blocks (2/CU), 8 waves;
//       wave w owns jb in [w*32, w*32+32), processed in pairs with register
//       double-buffering (pair in flight while pair computes). Emits edge
//       bitmask Mw; epilogue writes Upack (bf16 B-frags) directly.
//  k3 : prologue recovers per-row masked max of g from Mw bitmask; main loop
//       fused softmax weights + attention@U via MFMA + denominator; ELU.
//
// Fragment convention (self-consistent, round-1/3-proven):
//  element e of lane l <-> k = kblock*32 + (l>>4)*8 + e; A row / B col = l&15;
//  C/D: col = l&15, row = (l>>4)*4 + reg.
//  Bpack/Upack: frag[(kb*4+b)*64 + lane][e]  (s16x8 per lane)
//  Mask: Mw[(rowblk16*256 + jb)*8 + e] bit l = adj[rowblk16*16+(l&15)][jb*32+(l>>4)*8+e] > 0

#define N 8192

typedef float f32x4 __attribute__((ext_vector_type(4)));
typedef short s16x8 __attribute__((ext_vector_type(8)));
typedef unsigned long long u64;
typedef u64 u64x2 __attribute__((ext_vector_type(2)));

__device__ __forceinline__ unsigned short f2bf(float x) {
  unsigned u = __float_as_uint(x);
  u += 0x7FFFu + ((u >> 16) & 1u);   // RNE
  return (unsigned short)(u >> 16);
}
__device__ __forceinline__ unsigned pack2(unsigned short lo, unsigned short hi) {
  return (unsigned)lo | ((unsigned)hi << 16);
}

#define MFMA __builtin_amdgcn_mfma_f32_16x16x32_bf16

// ---------------- k1: Wh, f, g, Bpack ----------------
__global__ __launch_bounds__(256) void k1(const float* __restrict__ h,
                                          const float* __restrict__ W,
                                          const float* __restrict__ a,
                                          unsigned short* __restrict__ Bpack,
                                          float* __restrict__ f,
                                          float* __restrict__ g) {
  const int lane = threadIdx.x & 63;
  const int w = threadIdx.x >> 6;
  const int i = blockIdx.x * 4 + w;        // row
  const float* hrow = h + (size_t)i * 256;
  float acc = 0.f;
#pragma unroll 4
  for (int kb = 0; kb < 64; ++kb) {
    f32x4 hv = *(const f32x4*)(hrow + (kb << 2));
    acc += hv.x * W[((kb << 2) + 0) * 64 + lane];
    acc += hv.y * W[((kb << 2) + 1) * 64 + lane];
    acc += hv.z * W[((kb << 2) + 2) * 64 + lane];
    acc += hv.w * W[((kb << 2) + 3) * 64 + lane];
  }
  float s1 = acc * a[lane];
  float s2 = acc * a[64 + lane];
#pragma unroll
  for (int d = 32; d > 0; d >>= 1) {
    s1 += __shfl_xor(s1, d);
    s2 += __shfl_xor(s2, d);
  }
  if (lane == 0) { f[i] = s1; g[i] = s2; }
  const int kb = i >> 5;
  const int b = lane >> 4;
  const int lp = (lane & 15) | (((i >> 3) & 3) << 4);
  const int e = i & 7;
  Bpack[(((size_t)(kb * 4 + b)) * 64 + lp) * 8 + e] = f2bf(acc);
}

// ---------------- k2: U = adj@Wh (MFMA) + mask; Upack direct ----------------
__global__ __launch_bounds__(512, 4) void k2(const float* __restrict__ adj,
                                             const unsigned short* __restrict__ Bpack,
                                             unsigned short* __restrict__ Upack,
                                             u64* __restrict__ Mw) {
  __shared__ float red[8][64][16];   // 32 KB
  const int l = threadIdx.x & 63;
  const int w = threadIdx.x >> 6;
  const int i0 = blockIdx.x << 4;          // 16 rows/block
  const int r = l & 15, kg = l >> 4;
  const float* aprow = adj + (size_t)(i0 + r) * N + (kg << 3);
  const s16x8* Bv = (const s16x8*)Bpack;
  u64* mwb = Mw + (((size_t)(i0 >> 4)) << 11) + (((size_t)w) << 8);  // + (w*32)*8
  const int jb0 = w << 5;
  f32x4 acc0 = {0.f,0.f,0.f,0.f}, acc1 = acc0, acc2 = acc0, acc3 = acc0;
  f32x4 Aa, Ab, Ac, Ad, Ba, Bb, Bc, Bd;
  {
    const float* p = aprow + (jb0 << 5);
    Aa = *(const f32x4*)p;        Ab = *(const f32x4*)(p + 4);
    Ac = *(const f32x4*)(p + 32); Ad = *(const f32x4*)(p + 36);
    const float* q = p + 64;
    Ba = *(const f32x4*)q;        Bb = *(const f32x4*)(q + 4);
    Bc = *(const f32x4*)(q + 32); Bd = *(const f32x4*)(q + 36);
  }
#define K2STEP(Xa, Xb, Xc, Xd, uu, nu) {                                      \
    const int jbA = jb0 + (uu);                                               \
    const size_t bi = ((size_t)jbA << 8) + l;                                 \
    s16x8 f0 = Bv[bi],       f1 = Bv[bi + 64],                                \
          f2 = Bv[bi + 128], f3 = Bv[bi + 192];                               \
    s16x8 f4 = Bv[bi + 256], f5 = Bv[bi + 320],                               \
          f6 = Bv[bi + 384], f7 = Bv[bi + 448];                               \
    u64 b0 = __ballot(Xa.x > 0.f), b1 = __ballot(Xa.y > 0.f);                 \
    u64 b2 = __ballot(Xa.z > 0.f), b3 = __ballot(Xa.w > 0.f);                 \
    u64 b4 = __ballot(Xb.x > 0.f), b5 = __ballot(Xb.y > 0.f);                 \
    u64 b6 = __ballot(Xb.z > 0.f), b7 = __ballot(Xb.w > 0.f);                 \
    u64 c0 = __ballot(Xc.x > 0.f), c1 = __ballot(Xc.y > 0.f);                 \
    u64 c2 = __ballot(Xc.z > 0.f), c3 = __ballot(Xc.w > 0.f);                 \
    u64 c4 = __ballot(Xd.x > 0.f), c5 = __ballot(Xd.y > 0.f);                 \
    u64 c6 = __ballot(Xd.z > 0.f), c7 = __ballot(Xd.w > 0.f);                 \
    s16x8 af, ag;                                                             \
    af[0] = (Xa.x > 0.f) ? (short)0x3F80 : (short)0;                          \
    af[1] = (Xa.y > 0.f) ? (short)0x3F80 : (short)0;                          \
    af[2] = (Xa.z > 0.f) ? (short)0x3F80 : (short)0;                          \
    af[3] = (Xa.w > 0.f) ? (short)0x3F80 : (short)0;                          \
    af[4] = (Xb.x > 0.f) ? (short)0x3F80 : (short)0;                          \
    af[5] = (Xb.y > 0.f) ? (short)0x3F80 : (short)0;                          \
    af[6] = (Xb.z > 0.f) ? (short)0x3F80 : (short)0;                          \
    af[7] = (Xb.w > 0.f) ? (short)0x3F80 : (short)0;                          \
    ag[0] = (Xc.x > 0.f) ? (short)0x3F80 : (short)0;                          \
    ag[1] = (Xc.y > 0.f) ? (short)0x3F80 : (short)0;                          \
    ag[2] = (Xc.z > 0.f) ? (short)0x3F80 : (short)0;                          \
    ag[3] = (Xc.w > 0.f) ? (short)0x3F80 : (short)0;                          \
    ag[4] = (Xd.x > 0.f) ? (short)0x3F80 : (short)0;                          \
    ag[5] = (Xd.y > 0.f) ? (short)0x3F80 : (short)0;                          \
    ag[6] = (Xd.z > 0.f) ? (short)0x3F80 : (short)0;                          \
    ag[7] = (Xd.w > 0.f) ? (short)0x3F80 : (short)0;                          \
    { const float* pp = aprow + ((jb0 + (nu)) << 5);                          \
      Xa = *(const f32x4*)pp;        Xb = *(const f32x4*)(pp + 4);            \
      Xc = *(const f32x4*)(pp + 32); Xd = *(const f32x4*)(pp + 36); }         \
    if (l == 0) {                                                             \
      u64x2* mp = (u64x2*)(mwb + (((size_t)(uu)) << 3));                      \
      u64x2 v0; v0.x = b0; v0.y = b1;                                         \
      u64x2 v1; v1.x = b2; v1.y = b3;                                         \
      u64x2 v2; v2.x = b4; v2.y = b5;                                         \
      u64x2 v3; v3.x = b6; v3.y = b7;                                         \
      mp[0] = v0; mp[1] = v1; mp[2] = v2; mp[3] = v3;                         \
      u64x2* mq = (u64x2*)(mwb + (((size_t)((uu) + 1)) << 3));                \
      u64x2 w0; w0.x = c0; w0.y = c1;                                         \
      u64x2 w1; w1.x = c2; w1.y = c3;                                         \
      u64x2 w2; w2.x = c4; w2.y = c5;                                         \
      u64x2 w3; w3.x = c6; w3.y = c7;                                         \
      mq[0] = w0; mq[1] = w1; mq[2] = w2; mq[3] = w3;                         \
    }                                                                         \
    acc0 = MFMA(af, f0, acc0, 0, 0, 0);                                       \
    acc1 = MFMA(af, f1, acc1, 0, 0, 0);                                       \
    acc2 = MFMA(af, f2, acc2, 0, 0, 0);                                       \
    acc3 = MFMA(af, f3, acc3, 0, 0, 0);                                       \
    acc0 = MFMA(ag, f4, acc0, 0, 0, 0);                                       \
    acc1 = MFMA(ag, f5, acc1, 0, 0, 0);                                       \
    acc2 = MFMA(ag, f6, acc2, 0, 0, 0);                                       \
    acc3 = MFMA(ag, f7, acc3, 0, 0, 0);                                       \
  }
  for (int u = 0; u < 32; u += 4) {
    K2STEP(Aa, Ab, Ac, Ad, u,     (u + 4) & 31)
    K2STEP(Ba, Bb, Bc, Bd, u + 2, (u + 6) & 31)
  }
#undef K2STEP
#pragma unroll
  for (int q = 0; q < 4; ++q) {
    red[w][l][q] = acc0[q]; red[w][l][4 + q] = acc1[q];
    red[w][l][8 + q] = acc2[q]; red[w][l][12 + q] = acc3[q];
  }
  __syncthreads();
  const int tl = threadIdx.x & 63;
  const int b = (threadIdx.x >> 6) & 3;
  const int sE = threadIdx.x >> 8;
  const int reg0 = sE << 1;
  float u0 = 0.f, u1 = 0.f;
#pragma unroll
  for (int w8 = 0; w8 < 8; ++w8) {
    u0 += red[w8][tl][(b << 2) + reg0];
    u1 += red[w8][tl][(b << 2) + reg0 + 1];
  }
  const int k0 = i0 + ((tl >> 4) << 2) + reg0;
  const unsigned pkv = pack2(f2bf(u0), f2bf(u1));
  const int kbD = k0 >> 5, lgrp = (k0 >> 3) & 3, e0 = k0 & 7;
  *(unsigned*)((char*)Upack +
      ((size_t)((kbD << 2) + b) * 64 + ((tl & 15) | (lgrp << 4))) * 16 + (e0 << 1)) = pkv;
}

// ---------------- k3: Gmax prologue + fused softmax + attention@U + ELU ----------------
__global__ __launch_bounds__(512, 4) void k3(const u64* __restrict__ Mw,
                                             const unsigned short* __restrict__ Upack,
                                             const float* __restrict__ f,
                                             const float* __restrict__ g,
                                             float* __restrict__ out) {
  __shared__ float red[8][64][16];   // 32 KB
  __shared__ float wred[8][16];
  __shared__ float gred[8][16];
  const int l = threadIdx.x & 63;
  const int w = threadIdx.x >> 6;
  const int i0 = blockIdx.x << 4;
  const int r = l & 15, kg = l >> 4;
  const int jb0 = w << 5;
  const u64* mwb = Mw + (((size_t)(i0 >> 4)) << 11);
  const s16x8* Uv = (const s16x8*)Upack;
  // Phase 0: per-row masked max of g from bitmask
  float gmx = -INFINITY;
  for (int u = 0; u < 32; ++u) {
    const int jb = jb0 + u;
    const u64x2* mp = (const u64x2*)(mwb + ((size_t)jb << 3));
    u64x2 m01 = mp[0], m23 = mp[1], m45 = mp[2], m67 = mp[3];
    f32x4 g0 = *(const f32x4*)(g + (jb << 5) + (kg << 3));
    f32x4 g1 = *(const f32x4*)(g + (jb << 5) + (kg << 3) + 4);
    if ((m01.x >> l) & 1ull) gmx = fmaxf(gmx, g0.x);
    if ((m01.y >> l) & 1ull) gmx = fmaxf(gmx, g0.y);
    if ((m23.x >> l) & 1ull) gmx = fmaxf(gmx, g0.z);
    if ((m23.y >> l) & 1ull) gmx = fmaxf(gmx, g0.w);
    if ((m45.x >> l) & 1ull) gmx = fmaxf(gmx, g1.x);
    if ((m45.y >> l) & 1ull) gmx = fmaxf(gmx, g1.y);
    if ((m67.x >> l) & 1ull) gmx = fmaxf(gmx, g1.z);
    if ((m67.y >> l) & 1ull) gmx = fmaxf(gmx, g1.w);
  }
  gmx = fmaxf(gmx, __shfl_xor(gmx, 16));
  gmx = fmaxf(gmx, __shfl_xor(gmx, 32));
  if (l < 16) gred[w][l] = gmx;
  __syncthreads();
  float gm = gred[0][r];
#pragma unroll
  for (int w8 = 1; w8 < 8; ++w8) gm = fmaxf(gm, gred[w8][r]);
  const float fi = f[i0 + r];
  float m = fi + gm;
  m = fmaxf(m, 0.2f * m);                  // m_i = leaky(f_i + Gmax_i)
  // Phase 1: weights + MFMA P@Upack
  f32x4 acc0 = {0.f,0.f,0.f,0.f}, acc1 = acc0, acc2 = acc0, acc3 = acc0;
  float wsum = 0.f;
  u64x2 Am0, Am1, Am2, Am3, Bm0, Bm1, Bm2, Bm3;
  f32x4 Ag0, Ag1, Bg0, Bg1;
  {
    const u64x2* mp = (const u64x2*)(mwb + ((size_t)jb0 << 3));
    Am0 = mp[0]; Am1 = mp[1]; Am2 = mp[2]; Am3 = mp[3];
    Ag0 = *(const f32x4*)(g + (jb0 << 5) + (kg << 3));
    Ag1 = *(const f32x4*)(g + (jb0 << 5) + (kg << 3) + 4);
    const u64x2* mq = (const u64x2*)(mwb + ((size_t)(jb0 + 1) << 3));
    Bm0 = mq[0]; Bm1 = mq[1]; Bm2 = mq[2]; Bm3 = mq[3];
    Bg0 = *(const f32x4*)(g + ((jb0 + 1) << 5) + (kg << 3));
    Bg1 = *(const f32x4*)(g + ((jb0 + 1) << 5) + (kg << 3) + 4);
  }
#define K3W(dst, me, gv) {                                                    \
    float x_ = fi + (gv);                                                     \
    float ev_ = fmaxf(x_, 0.2f * x_);                                         \
    float wv_ = __expf(ev_ - m);                                              \
    wv_ = (((me) >> l) & 1ull) ? wv_ : 0.f;                                   \
    wsum += wv_; dst = (short)f2bf(wv_); }
#define K3STEP(Xm0, Xm1, Xm2, Xm3, Xg0, Xg1, uu, nu) {                        \
    const int jbA = jb0 + (uu);                                               \
    const size_t bi = ((size_t)jbA << 8) + l;                                 \
    s16x8 f0 = Uv[bi],       f1 = Uv[bi + 64],                                \
          f2 = Uv[bi + 128], f3 = Uv[bi + 192];                               \
    s16x8 pf;                                                                 \
    K3W(pf[0], Xm0.x, Xg0.x) K3W(pf[1], Xm0.y, Xg0.y)                         \
    K3W(pf[2], Xm1.x, Xg0.z) K3W(pf[3], Xm1.y, Xg0.w)                         \
    K3W(pf[4], Xm2.x, Xg1.x) K3W(pf[5], Xm2.y, Xg1.y)                         \
    K3W(pf[6], Xm3.x, Xg1.z) K3W(pf[7], Xm3.y, Xg1.w)                         \
    { const int jn = jb0 + (nu);                                              \
      const u64x2* mp2 = (const u64x2*)(mwb + ((size_t)jn << 3));             \
      Xm0 = mp2[0]; Xm1 = mp2[1]; Xm2 = mp2[2]; Xm3 = mp2[3];                 \
      Xg0 = *(const f32x4*)(g + (jn << 5) + (kg << 3));                       \
      Xg1 = *(const f32x4*)(g + (jn << 5) + (kg << 3) + 4); }                 \
    acc0 = MFMA(pf, f0, acc0, 0, 0, 0);                                       \
    acc1 = MFMA(pf, f1, acc1, 0, 0, 0);                                       \
    acc2 = MFMA(pf, f2, acc2, 0, 0, 0);                                       \
    acc3 = MFMA(pf, f3, acc3, 0, 0, 0);                                       \
  }
  for (int u = 0; u < 32; u += 2) {
    K3STEP(Am0, Am1, Am2, Am3, Ag0, Ag1, u,     (u + 2) & 31)
    K3STEP(Bm0, Bm1, Bm2, Bm3, Bg0, Bg1, u + 1, (u + 3) & 31)
  }
#undef K3STEP
#undef K3W
  wsum += __shfl_xor(wsum, 16);
  wsum += __shfl_xor(wsum, 32);
  if (l < 16) wred[w][l] = wsum;
#pragma unroll
  for (int q = 0; q < 4; ++q) {
    red[w][l][q] = acc0[q]; red[w][l][4 + q] = acc1[q];
    red[w][l][8 + q] = acc2[q]; red[w][l][12 + q] = acc3[q];
  }
  __syncthreads();
  const int tl = threadIdx.x & 63;
  const int b = (threadIdx.x >> 6) & 3;
  const int sE = threadIdx.x >> 8;
#pragma unroll
  for (int q = 0; q < 2; ++q) {
    const int reg = (sE << 1) + q;
    const int idx = (b << 2) + reg;
    const int row = ((tl >> 4) << 2) + reg;
    float sv = 0.f, dv = 0.f;
#pragma unroll
    for (int w8 = 0; w8 < 8; ++w8) {
      sv += red[w8][tl][idx];
      dv += wred[w8][row];
    }
    dv = (dv > 0.f) ? dv : 1.f;            // defensive: avoid 0/0
    float v = sv / dv;
    v = (v > 0.f) ? v : (__expf(v) - 1.f); // ELU
    out[(size_t)(i0 + row) * 64 + (b << 4) + (tl & 15)] = v;
  }
}

extern "C" void kernel_launch(void* const* d_in, const int* in_sizes, int n_in,
                              void* d_out, int out_size, void* d_ws, size_t ws_size,
                              hipStream_t stream) {
  const float* h   = (const float*)d_in[0];
  const float* adj = (const float*)d_in[1];
  const float* W   = (const float*)d_in[2];
  const float* a   = (const float*)d_in[3];
  float* out = (float*)d_out;
  char* ws = (char*)d_ws;
  unsigned short* Bpack = (unsigned short*)(ws);                   // 1 MB
  unsigned short* Upack = (unsigned short*)(ws + (1u << 20));      // 1 MB
  float* f    = (float*)(ws + (2u << 20));                         // 32 KB
  float* g    = (float*)(ws + (2u << 20) + 32768u);                // 32 KB
  u64* Mw = (u64*)(ws + (3u << 20));                               // 8 MB

  hipLaunchKernelGGL(k1, dim3(2048), dim3(256), 0, stream, h, W, a, Bpack, f, g);
  hipLaunchKernelGGL(k2, dim3(512), dim3(512), 0, stream, adj, Bpack, Upack, Mw);
  hipLaunchKernelGGL(k3, dim3(512), dim3(512), 0, stream, Mw, Upack, f, g, out);
}

// Round 5
// 147.434 us; speedup vs baseline: 1.4682x; 1.2492x over previous
//
#include <hip/hip_runtime.h>
#include <hip/hip_bf16.h>

// GAT layer, N=8192, F_IN=256, F_OUT=64.
//  k1 : Wh = h@W; f,g projections; Bpack (bf16 B-frags of Wh).
//  k2a: pure-stream mask builder. Wave = one adj row, dense f32x4 loads,
//       4 ballots/KB. ML[i][c][q] bit l = adj[i][c*256 + l*4 + q] > 0.
//  k2b: U = adj@Wh from bitmask via MFMA (A-frag = cndmask of mask bits);
//       masked Gmax of g; epilogue writes Upack (bf16 B-frags) + Gmax.
//  k3 : fused softmax weights + attention@U via MFMA + denominator; ELU.
//
// Fragment convention (proven rounds 1/3/4):
//  element e of lane l <-> k = kblock*32 + (l>>4)*8 + e; A row / B col = l&15;
//  C/D: col = l&15, row = (l>>4)*4 + reg.
//  Bpack/Upack: frag[(kb*4+b)*64 + lane][e]  (s16x8 per lane)
// Mask bit for (row i, col j): word ML[i*128 + (j>>8)*4 + (j&3)], bit (j>>2)&63.
//  For fragment element (r, jb, kg, e): j = jb*32+kg*8+e -> q = e&3,
//  shift = (jb&7)*8 + kg*2 + (e>>2), word-chunk c = jb>>3.

#define N 8192

typedef float f32x4 __attribute__((ext_vector_type(4)));
typedef short s16x8 __attribute__((ext_vector_type(8)));
typedef unsigned long long u64;
typedef u64 u64x2 __attribute__((ext_vector_type(2)));

__device__ __forceinline__ unsigned short f2bf(float x) {
  unsigned u = __float_as_uint(x);
  u += 0x7FFFu + ((u >> 16) & 1u);   // RNE
  return (unsigned short)(u >> 16);
}
__device__ __forceinline__ unsigned pack2(unsigned short lo, unsigned short hi) {
  return (unsigned)lo | ((unsigned)hi << 16);
}

#define MFMA __builtin_amdgcn_mfma_f32_16x16x32_bf16

// ---------------- k1: Wh, f, g, Bpack (round-4-proven) ----------------
__global__ __launch_bounds__(256) void k1(const float* __restrict__ h,
                                          const float* __restrict__ W,
                                          const float* __restrict__ a,
                                          unsigned short* __restrict__ Bpack,
                                          float* __restrict__ f,
                                          float* __restrict__ g) {
  const int lane = threadIdx.x & 63;
  const int w = threadIdx.x >> 6;
  const int i = blockIdx.x * 4 + w;        // row
  const float* hrow = h + (size_t)i * 256;
  float acc = 0.f;
#pragma unroll 4
  for (int kb = 0; kb < 64; ++kb) {
    f32x4 hv = *(const f32x4*)(hrow + (kb << 2));
    acc += hv.x * W[((kb << 2) + 0) * 64 + lane];
    acc += hv.y * W[((kb << 2) + 1) * 64 + lane];
    acc += hv.z * W[((kb << 2) + 2) * 64 + lane];
    acc += hv.w * W[((kb << 2) + 3) * 64 + lane];
  }
  float s1 = acc * a[lane];
  float s2 = acc * a[64 + lane];
#pragma unroll
  for (int d = 32; d > 0; d >>= 1) {
    s1 += __shfl_xor(s1, d);
    s2 += __shfl_xor(s2, d);
  }
  if (lane == 0) { f[i] = s1; g[i] = s2; }
  const int kb = i >> 5;
  const int b = lane >> 4;
  const int lp = (lane & 15) | (((i >> 3) & 3) << 4);
  const int e = i & 7;
  Bpack[(((size_t)(kb * 4 + b)) * 64 + lp) * 8 + e] = f2bf(acc);
}

// ---------------- k2a: pure-stream bitmask builder ----------------
__global__ __launch_bounds__(256, 8) void k2a(const float* __restrict__ adj,
                                              u64* __restrict__ ML) {
  const int l = threadIdx.x & 63;
  const int w = threadIdx.x >> 6;
  const int i = (blockIdx.x << 2) + w;     // one row per wave
  const float* ap = adj + (size_t)i * N + (l << 2);
  u64* mp = ML + (size_t)i * 128;
  for (int cc = 0; cc < 32; cc += 4) {
    f32x4 v0 = *(const f32x4*)(ap + ((cc + 0) << 8));
    f32x4 v1 = *(const f32x4*)(ap + ((cc + 1) << 8));
    f32x4 v2 = *(const f32x4*)(ap + ((cc + 2) << 8));
    f32x4 v3 = *(const f32x4*)(ap + ((cc + 3) << 8));
    u64 b0  = __ballot(v0.x > 0.f), b1  = __ballot(v0.y > 0.f);
    u64 b2  = __ballot(v0.z > 0.f), b3  = __ballot(v0.w > 0.f);
    u64 b4  = __ballot(v1.x > 0.f), b5  = __ballot(v1.y > 0.f);
    u64 b6  = __ballot(v1.z > 0.f), b7  = __ballot(v1.w > 0.f);
    u64 b8  = __ballot(v2.x > 0.f), b9  = __ballot(v2.y > 0.f);
    u64 b10 = __ballot(v2.z > 0.f), b11 = __ballot(v2.w > 0.f);
    u64 b12 = __ballot(v3.x > 0.f), b13 = __ballot(v3.y > 0.f);
    u64 b14 = __ballot(v3.z > 0.f), b15 = __ballot(v3.w > 0.f);
    if (l == 0) {
      u64x2* q = (u64x2*)(mp + (cc << 2));
      u64x2 t0; t0.x = b0;  t0.y = b1;  q[0] = t0;
      u64x2 t1; t1.x = b2;  t1.y = b3;  q[1] = t1;
      u64x2 t2; t2.x = b4;  t2.y = b5;  q[2] = t2;
      u64x2 t3; t3.x = b6;  t3.y = b7;  q[3] = t3;
      u64x2 t4; t4.x = b8;  t4.y = b9;  q[4] = t4;
      u64x2 t5; t5.x = b10; t5.y = b11; q[5] = t5;
      u64x2 t6; t6.x = b12; t6.y = b13; q[6] = t6;
      u64x2 t7; t7.x = b14; t7.y = b15; q[7] = t7;
    }
  }
}

// ---------------- k2b: U = adj@Wh from mask + Gmax; Upack direct ----------------
__global__ __launch_bounds__(512, 4) void k2b(const u64* __restrict__ ML,
                                              const unsigned short* __restrict__ Bpack,
                                              const float* __restrict__ g,
                                              unsigned short* __restrict__ Upack,
                                              float* __restrict__ Gmax) {
  __shared__ float red[8][64][16];   // 32 KB
  __shared__ float gred[8][16];
  const int l = threadIdx.x & 63;
  const int w = threadIdx.x >> 6;
  const int i0 = blockIdx.x << 4;          // 16 rows/block
  const int r = l & 15, kg = l >> 4;
  const s16x8* Bv = (const s16x8*)Bpack;
  const u64x2* mrow = (const u64x2*)(ML + (size_t)(i0 + r) * 128);
  const int sh0 = kg << 1;
  f32x4 acc0 = {0.f,0.f,0.f,0.f}, acc1 = acc0, acc2 = acc0, acc3 = acc0;
  float gmx = -INFINITY;
  for (int cc = 0; cc < 4; ++cc) {
    const int c = (w << 2) + cc;           // chunk of 256 cols
    u64x2 m01 = mrow[(c << 1)], m23 = mrow[(c << 1) + 1];
    const u64 wq0 = m01.x, wq1 = m01.y, wq2 = m23.x, wq3 = m23.y;
#pragma unroll
    for (int j7 = 0; j7 < 8; ++j7) {
      const int jb = (c << 3) + j7;
      f32x4 g0 = *(const f32x4*)(g + (jb << 5) + (kg << 3));
      f32x4 g1 = *(const f32x4*)(g + (jb << 5) + (kg << 3) + 4);
      const int shb = (j7 << 3) + sh0;
      const unsigned bit0 = (unsigned)(wq0 >> shb) & 1u;
      const unsigned bit1 = (unsigned)(wq1 >> shb) & 1u;
      const unsigned bit2 = (unsigned)(wq2 >> shb) & 1u;
      const unsigned bit3 = (unsigned)(wq3 >> shb) & 1u;
      const unsigned bit4 = (unsigned)(wq0 >> (shb + 1)) & 1u;
      const unsigned bit5 = (unsigned)(wq1 >> (shb + 1)) & 1u;
      const unsigned bit6 = (unsigned)(wq2 >> (shb + 1)) & 1u;
      const unsigned bit7 = (unsigned)(wq3 >> (shb + 1)) & 1u;
      s16x8 af;
      af[0] = bit0 ? (short)0x3F80 : (short)0;
      af[1] = bit1 ? (short)0x3F80 : (short)0;
      af[2] = bit2 ? (short)0x3F80 : (short)0;
      af[3] = bit3 ? (short)0x3F80 : (short)0;
      af[4] = bit4 ? (short)0x3F80 : (short)0;
      af[5] = bit5 ? (short)0x3F80 : (short)0;
      af[6] = bit6 ? (short)0x3F80 : (short)0;
      af[7] = bit7 ? (short)0x3F80 : (short)0;
      if (bit0) gmx = fmaxf(gmx, g0.x);
      if (bit1) gmx = fmaxf(gmx, g0.y);
      if (bit2) gmx = fmaxf(gmx, g0.z);
      if (bit3) gmx = fmaxf(gmx, g0.w);
      if (bit4) gmx = fmaxf(gmx, g1.x);
      if (bit5) gmx = fmaxf(gmx, g1.y);
      if (bit6) gmx = fmaxf(gmx, g1.z);
      if (bit7) gmx = fmaxf(gmx, g1.w);
      const size_t bi = ((size_t)jb << 8) + l;
      s16x8 f0 = Bv[bi], f1 = Bv[bi + 64], f2 = Bv[bi + 128], f3 = Bv[bi + 192];
      acc0 = MFMA(af, f0, acc0, 0, 0, 0);
      acc1 = MFMA(af, f1, acc1, 0, 0, 0);
      acc2 = MFMA(af, f2, acc2, 0, 0, 0);
      acc3 = MFMA(af, f3, acc3, 0, 0, 0);
    }
  }
  gmx = fmaxf(gmx, __shfl_xor(gmx, 16));
  gmx = fmaxf(gmx, __shfl_xor(gmx, 32));
  if (l < 16) gred[w][l] = gmx;
#pragma unroll
  for (int q = 0; q < 4; ++q) {
    red[w][l][q] = acc0[q]; red[w][l][4 + q] = acc1[q];
    red[w][l][8 + q] = acc2[q]; red[w][l][12 + q] = acc3[q];
  }
  __syncthreads();
  const int tl = threadIdx.x & 63;
  const int b = (threadIdx.x >> 6) & 3;
  const int sE = threadIdx.x >> 8;
  const int reg0 = sE << 1;
  float u0 = 0.f, u1 = 0.f;
#pragma unroll
  for (int w8 = 0; w8 < 8; ++w8) {
    u0 += red[w8][tl][(b << 2) + reg0];
    u1 += red[w8][tl][(b << 2) + reg0 + 1];
  }
  const int k0 = i0 + ((tl >> 4) << 2) + reg0;
  const unsigned pkv = pack2(f2bf(u0), f2bf(u1));
  const int kbD = k0 >> 5, lgrp = (k0 >> 3) & 3, e0 = k0 & 7;
  *(unsigned*)((char*)Upack +
      ((size_t)((kbD << 2) + b) * 64 + ((tl & 15) | (lgrp << 4))) * 16 + (e0 << 1)) = pkv;
  if (threadIdx.x < 16) {
    float gm = gred[0][threadIdx.x];
#pragma unroll
    for (int w8 = 1; w8 < 8; ++w8) gm = fmaxf(gm, gred[w8][threadIdx.x]);
    Gmax[i0 + threadIdx.x] = gm;
  }
}

// ---------------- k3: fused softmax + attention@U + ELU ----------------
__global__ __launch_bounds__(512, 4) void k3(const u64* __restrict__ ML,
                                             const unsigned short* __restrict__ Upack,
                                             const float* __restrict__ f,
                                             const float* __restrict__ g,
                                             const float* __restrict__ Gmax,
                                             float* __restrict__ out) {
  __shared__ float red[8][64][16];   // 32 KB
  __shared__ float wred[8][16];
  const int l = threadIdx.x & 63;
  const int w = threadIdx.x >> 6;
  const int i0 = blockIdx.x << 4;
  const int r = l & 15, kg = l >> 4;
  const float fi = f[i0 + r];
  float m = fi + Gmax[i0 + r];
  m = fmaxf(m, 0.2f * m);                  // m_i = leaky(f_i + Gmax_i)
  const s16x8* Uv = (const s16x8*)Upack;
  const u64x2* mrow = (const u64x2*)(ML + (size_t)(i0 + r) * 128);
  const int sh0 = kg << 1;
  f32x4 acc0 = {0.f,0.f,0.f,0.f}, acc1 = acc0, acc2 = acc0, acc3 = acc0;
  float wsum = 0.f;
  for (int cc = 0; cc < 4; ++cc) {
    const int c = (w << 2) + cc;
    u64x2 m01 = mrow[(c << 1)], m23 = mrow[(c << 1) + 1];
    const u64 wq0 = m01.x, wq1 = m01.y, wq2 = m23.x, wq3 = m23.y;
#pragma unroll
    for (int j7 = 0; j7 < 8; ++j7) {
      const int jb = (c << 3) + j7;
      f32x4 g0 = *(const f32x4*)(g + (jb << 5) + (kg << 3));
      f32x4 g1 = *(const f32x4*)(g + (jb << 5) + (kg << 3) + 4);
      const int shb = (j7 << 3) + sh0;
      s16x8 pf;
      float wt;
#define K3W(idx, wq, sh, gv) {                                  \
      const unsigned bit_ = (unsigned)((wq) >> (sh)) & 1u;      \
      float x_ = fi + (gv);                                     \
      float ev_ = fmaxf(x_, 0.2f * x_);                         \
      wt = __expf(ev_ - m);                                     \
      wt = bit_ ? wt : 0.f;                                     \
      wsum += wt; pf[idx] = (short)f2bf(wt); }
      K3W(0, wq0, shb,     g0.x)
      K3W(1, wq1, shb,     g0.y)
      K3W(2, wq2, shb,     g0.z)
      K3W(3, wq3, shb,     g0.w)
      K3W(4, wq0, shb + 1, g1.x)
      K3W(5, wq1, shb + 1, g1.y)
      K3W(6, wq2, shb + 1, g1.z)
      K3W(7, wq3, shb + 1, g1.w)
#undef K3W
      const size_t bi = ((size_t)jb << 8) + l;
      s16x8 f0 = Uv[bi], f1 = Uv[bi + 64], f2 = Uv[bi + 128], f3 = Uv[bi + 192];
      acc0 = MFMA(pf, f0, acc0, 0, 0, 0);
      acc1 = MFMA(pf, f1, acc1, 0, 0, 0);
      acc2 = MFMA(pf, f2, acc2, 0, 0, 0);
      acc3 = MFMA(pf, f3, acc3, 0, 0, 0);
    }
  }
  wsum += __shfl_xor(wsum, 16);
  wsum += __shfl_xor(wsum, 32);
  if (l < 16) wred[w][l] = wsum;
#pragma unroll
  for (int q = 0; q < 4; ++q) {
    red[w][l][q] = acc0[q]; red[w][l][4 + q] = acc1[q];
    red[w][l][8 + q] = acc2[q]; red[w][l][12 + q] = acc3[q];
  }
  __syncthreads();
  const int tl = threadIdx.x & 63;
  const int b = (threadIdx.x >> 6) & 3;
  const int sE = threadIdx.x >> 8;
#pragma unroll
  for (int q = 0; q < 2; ++q) {
    const int reg = (sE << 1) + q;
    const int idx = (b << 2) + reg;
    const int row = ((tl >> 4) << 2) + reg;
    float sv = 0.f, dv = 0.f;
#pragma unroll
    for (int w8 = 0; w8 < 8; ++w8) {
      sv += red[w8][tl][idx];
      dv += wred[w8][row];
    }
    dv = (dv > 0.f) ? dv : 1.f;            // defensive: avoid 0/0
    float v = sv / dv;
    v = (v > 0.f) ? v : (__expf(v) - 1.f); // ELU
    out[(size_t)(i0 + row) * 64 + (b << 4) + (tl & 15)] = v;
  }
}

extern "C" void kernel_launch(void* const* d_in, const int* in_sizes, int n_in,
                              void* d_out, int out_size, void* d_ws, size_t ws_size,
                              hipStream_t stream) {
  const float* h   = (const float*)d_in[0];
  const float* adj = (const float*)d_in[1];
  const float* W   = (const float*)d_in[2];
  const float* a   = (const float*)d_in[3];
  float* out = (float*)d_out;
  char* ws = (char*)d_ws;
  unsigned short* Bpack = (unsigned short*)(ws);                   // 1 MB
  unsigned short* Upack = (unsigned short*)(ws + (1u << 20));      // 1 MB
  float* f    = (float*)(ws + (2u << 20));                         // 32 KB
  float* g    = (float*)(ws + (2u << 20) + 32768u);                // 32 KB
  float* Gmax = (float*)(ws + (2u << 20) + 65536u);                // 32 KB
  u64* ML = (u64*)(ws + (3u << 20));                               // 8 MB

  hipLaunchKernelGGL(k1,  dim3(2048), dim3(256), 0, stream, h, W, a, Bpack, f, g);
  hipLaunchKernelGGL(k2a, dim3(2048), dim3(256), 0, stream, adj, ML);
  hipLaunchKernelGGL(k2b, dim3(512), dim3(512), 0, stream, ML, Bpack, g, Upack, Gmax);
  hipLaunchKernelGGL(k3,  dim3(512), dim3(512), 0, stream, ML, Upack, f, g, Gmax, out);
}